// Round 1
// baseline (610.353 us; speedup 1.0000x reference)
//
#include <hip/hip_runtime.h>
#include <hip/hip_bf16.h>

#define B_ 32
#define S_ 256
#define E_ 768
#define H_ 32
#define D_ 24
#define NTOT 1664   // 768 (q) + 768 (k) + 96 (vw) + 32 pad
#define LK 40       // LDS row stride (bf16 elems) for 32-wide K tiles

typedef __hip_bfloat16 bf16;
typedef __attribute__((ext_vector_type(8))) short short8;
typedef __attribute__((ext_vector_type(4))) float floatx4;
typedef __attribute__((ext_vector_type(2))) float f32x2;

// ---------------------------------------------------------------------------
// feats fp32 -> bf16, 4 elems/thread
// ---------------------------------------------------------------------------
__global__ __launch_bounds__(256) void cast_feats(
    const float* __restrict__ in, bf16* __restrict__ outp, int n4)
{
  int i = blockIdx.x * 256 + threadIdx.x;
  if (i < n4) {
    float4 v = reinterpret_cast<const float4*>(in)[i];
    union { ushort4 u; bf16 b[4]; } pk;
    pk.b[0] = (bf16)v.x; pk.b[1] = (bf16)v.y;
    pk.b[2] = (bf16)v.z; pk.b[3] = (bf16)v.w;
    reinterpret_cast<ushort4*>(outp)[i] = pk.u;
  }
}

// ---------------------------------------------------------------------------
// Pack transposed bf16 weights Wt[n][k] + fused bias biasf[1664].
// ---------------------------------------------------------------------------
__global__ __launch_bounds__(256) void prep_pack(
    const float* __restrict__ Wq, const float* __restrict__ Wk,
    const float* __restrict__ Wv,
    const float* __restrict__ bq, const float* __restrict__ bk,
    const float* __restrict__ bv,
    const float* __restrict__ Wfx, const float* __restrict__ Wfy,
    const float* __restrict__ Wfz,
    bf16* __restrict__ Wt, float* __restrict__ biasf)
{
  const float qscale = 0.20412414523193154f;  // 24^-0.5
  int gid = blockIdx.x * 256 + threadIdx.x;
  if (gid < NTOT * E_) {
    int n = gid / E_, k = gid % E_;
    float val;
    if (n < 768) {
      val = Wq[(size_t)k * E_ + n] * qscale;
    } else if (n < 1536) {
      val = Wk[(size_t)k * E_ + (n - 768)];
    } else if (n < 1632) {
      int nn = n - 1536, x = nn >> 5, h = nn & 31;
      const float* Wf = (x == 0) ? Wfx : (x == 1 ? Wfy : Wfz);
      float s = 0.f;
      #pragma unroll
      for (int c = 0; c < D_; c++)
        s += Wv[(size_t)k * E_ + h * D_ + c] * Wf[h * D_ + c];
      val = s;
    } else {
      val = 0.f;
    }
    Wt[gid] = (bf16)val;
  } else {
    int n = gid - NTOT * E_;
    if (n < NTOT) {
      float val;
      if (n < 768) {
        val = bq[n] * qscale;
      } else if (n < 1536) {
        val = bk[n - 768];
      } else if (n < 1632) {
        int nn = n - 1536, x = nn >> 5, h = nn & 31;
        const float* Wf = (x == 0) ? Wfx : (x == 1 ? Wfy : Wfz);
        float s = 0.f;
        #pragma unroll
        for (int c = 0; c < D_; c++)
          s += bv[h * D_ + c] * Wf[h * D_ + c];
        val = s;
      } else {
        val = 0.f;
      }
      biasf[n] = val;
    }
  }
}

// ---------------------------------------------------------------------------
// MFMA GEMM with 1-stage register prefetch (unchanged this round).
// ---------------------------------------------------------------------------
__global__ __launch_bounds__(256) void gemm_qkv(
    const bf16* __restrict__ A, const bf16* __restrict__ Wt,
    const float* __restrict__ biasf,
    bf16* __restrict__ qout, bf16* __restrict__ kout,
    float* __restrict__ vwout)
{
  __shared__ __align__(16) short As[128 * LK];
  __shared__ __align__(16) short Bs[128 * LK];
  int tid = threadIdx.x;
  int m0 = blockIdx.y * 128, n0 = blockIdx.x * 128;
  int lrow = tid >> 2, lcol = (tid & 3) * 8;
  int wave = tid >> 6, lane = tid & 63;
  int wm = (wave >> 1) * 64, wn = (wave & 1) * 64;
  int fr = lane & 15, quad = lane >> 4;

  floatx4 acc[4][4];
  const floatx4 zero = {0.f, 0.f, 0.f, 0.f};
  #pragma unroll
  for (int i = 0; i < 4; i++)
    #pragma unroll
    for (int j = 0; j < 4; j++) acc[i][j] = zero;

  const bf16* Aptr = A + (size_t)(m0 + lrow) * E_ + lcol;
  const bf16* Bptr = Wt + (size_t)(n0 + lrow) * E_ + lcol;
  float4 av0 = *reinterpret_cast<const float4*>(Aptr);
  float4 av1 = *reinterpret_cast<const float4*>(Aptr + (size_t)64 * E_);
  float4 bv0 = *reinterpret_cast<const float4*>(Bptr);
  float4 bv1 = *reinterpret_cast<const float4*>(Bptr + (size_t)64 * E_);

  for (int k0 = 0; k0 < E_; k0 += 32) {
    __syncthreads();  // previous iter's frag reads complete
    *reinterpret_cast<float4*>(&As[lrow * LK + lcol]) = av0;
    *reinterpret_cast<float4*>(&As[(lrow + 64) * LK + lcol]) = av1;
    *reinterpret_cast<float4*>(&Bs[lrow * LK + lcol]) = bv0;
    *reinterpret_cast<float4*>(&Bs[(lrow + 64) * LK + lcol]) = bv1;
    __syncthreads();
    if (k0 + 32 < E_) {  // prefetch next K-tile into registers
      av0 = *reinterpret_cast<const float4*>(Aptr + k0 + 32);
      av1 = *reinterpret_cast<const float4*>(Aptr + (size_t)64 * E_ + k0 + 32);
      bv0 = *reinterpret_cast<const float4*>(Bptr + k0 + 32);
      bv1 = *reinterpret_cast<const float4*>(Bptr + (size_t)64 * E_ + k0 + 32);
    }
    short8 af[4], bfr[4];
    #pragma unroll
    for (int t = 0; t < 4; t++)
      af[t] = *reinterpret_cast<const short8*>(
          &As[(wm + t * 16 + fr) * LK + quad * 8]);
    #pragma unroll
    for (int t = 0; t < 4; t++)
      bfr[t] = *reinterpret_cast<const short8*>(
          &Bs[(wn + t * 16 + fr) * LK + quad * 8]);
    #pragma unroll
    for (int ti = 0; ti < 4; ti++)
      #pragma unroll
      for (int tj = 0; tj < 4; tj++)
        acc[ti][tj] = __builtin_amdgcn_mfma_f32_16x16x32_bf16(
            af[ti], bfr[tj], acc[ti][tj], 0, 0, 0);
  }

  // epilogue: C/D layout col = lane&15, row = quad*4 + r
  #pragma unroll
  for (int ti = 0; ti < 4; ti++) {
    #pragma unroll
    for (int tj = 0; tj < 4; tj++) {
      int n = n0 + wn + tj * 16 + fr;
      float bias = biasf[n];
      #pragma unroll
      for (int r = 0; r < 4; r++) {
        int m = m0 + wm + ti * 16 + quad * 4 + r;
        int b = m >> 8, s = m & 255;
        float val = acc[ti][tj][r] + bias;
        if (n < 768) {
          int h = n / 24, d = n - h * 24;
          qout[(((size_t)b * H_ + h) * S_ + s) * D_ + d] = (bf16)val;
        } else if (n < 1536) {
          int n2 = n - 768;
          int h = n2 / 24, d = n2 - h * 24;
          kout[(((size_t)b * H_ + h) * S_ + s) * D_ + d] = (bf16)val;
        } else if (n < 1632) {
          int nn = n - 1536, x = nn >> 5, h = nn & 31;
          vwout[(((size_t)x * B_ + b) * H_ + h) * S_ + s] = val;
        }
      }
    }
  }
}

// ---------------------------------------------------------------------------
// Attention v3: lane-owns-s. Grid = B*H = 1024 blocks x 256 threads;
// thread == one s-row. K rows + vw staged as f32 in LDS (broadcast reads,
// conflict-free); q in registers. Softmax is THREAD-LOCAL: constant-shift
// exp (exp(sc-4)/sum == softmax exactly), so zero cross-lane reductions.
// bias/dp read as per-lane float4 streams with 1-iter register prefetch.
// ---------------------------------------------------------------------------
__global__ __launch_bounds__(256) void attn_kernel(
    const bf16* __restrict__ qg, const bf16* __restrict__ kg,
    const float* __restrict__ vwg, const float* __restrict__ biasg,
    const float* __restrict__ dpg, float* __restrict__ out)
{
  // kv[t][0..23] = K row (f32), [24..26] = vw x/y/z, [27] = pad
  __shared__ __align__(16) float kv[S_][28];
  int bh = blockIdx.x;            // 0..1023
  int b = bh >> 5, h = bh & 31;
  int s = threadIdx.x;            // 0..255, thread == s-row

  // ---- stage K row s (24 bf16 -> f32) + vw into LDS (one-time) ----
  {
    const short8* kr8 = reinterpret_cast<const short8*>(
        kg + ((size_t)bh * S_ + s) * D_);
    #pragma unroll
    for (int i = 0; i < 3; i++) {
      short8 kk = kr8[i];
      float4 f0, f1;
      union { short u; bf16 bb; } cv;
      cv.u = kk[0]; f0.x = (float)cv.bb;
      cv.u = kk[1]; f0.y = (float)cv.bb;
      cv.u = kk[2]; f0.z = (float)cv.bb;
      cv.u = kk[3]; f0.w = (float)cv.bb;
      cv.u = kk[4]; f1.x = (float)cv.bb;
      cv.u = kk[5]; f1.y = (float)cv.bb;
      cv.u = kk[6]; f1.z = (float)cv.bb;
      cv.u = kk[7]; f1.w = (float)cv.bb;
      *reinterpret_cast<float4*>(&kv[s][i * 8]) = f0;
      *reinterpret_cast<float4*>(&kv[s][i * 8 + 4]) = f1;
    }
    float4 vwp;
    vwp.x = vwg[(((size_t)0 * B_ + b) * H_ + h) * S_ + s];
    vwp.y = vwg[(((size_t)1 * B_ + b) * H_ + h) * S_ + s];
    vwp.z = vwg[(((size_t)2 * B_ + b) * H_ + h) * S_ + s];
    vwp.w = 0.f;
    *reinterpret_cast<float4*>(&kv[s][24]) = vwp;
  }

  // ---- q row s -> 12 packed f32x2 registers ----
  f32x2 qd[12];
  {
    const short8* qr8 = reinterpret_cast<const short8*>(
        qg + ((size_t)bh * S_ + s) * D_);
    #pragma unroll
    for (int i = 0; i < 3; i++) {
      short8 qq = qr8[i];
      #pragma unroll
      for (int j = 0; j < 4; j++) {
        union { short u; bf16 bb; } a, c;
        a.u = qq[2 * j]; c.u = qq[2 * j + 1];
        f32x2 t2; t2.x = (float)a.bb; t2.y = (float)c.bb;
        qd[i * 4 + j] = t2;
      }
    }
  }
  __syncthreads();

  const float* biasp = biasg + (size_t)bh * S_ * S_ + (size_t)s * S_;
  const float* dpp   = dpg + (size_t)(b * S_ + s) * S_ * 3;

  float l = 0.f, ax = 0.f, ay = 0.f, az = 0.f;

  // 4-t group: scores from LDS-broadcast K, thread-local exp + accumulate
  auto group = [&](int tb, float4 bias4, float4 d0, float4 d1, float4 d2) {
    float dx[4] = {d0.x, d0.w, d1.z, d2.y};
    float dy[4] = {d0.y, d1.x, d1.w, d2.z};
    float dz[4] = {d0.z, d1.y, d2.x, d2.w};
    float bb[4] = {bias4.x, bias4.y, bias4.z, bias4.w};
    #pragma unroll
    for (int j = 0; j < 4; j++) {
      const float4* krow4 = reinterpret_cast<const float4*>(&kv[tb + j][0]);
      f32x2 acc2; acc2.x = 0.f; acc2.y = 0.f;
      #pragma unroll
      for (int i = 0; i < 6; i++) {
        float4 k4 = krow4[i];
        f32x2 klo; klo.x = k4.x; klo.y = k4.y;
        f32x2 khi; khi.x = k4.z; khi.y = k4.w;
        acc2 += qd[2 * i] * klo;
        acc2 += qd[2 * i + 1] * khi;
      }
      float4 vw4 = krow4[6];
      // constant shift -4 replaces max-subtraction: exp(sc-4)/sum(exp(sc-4))
      // == softmax exactly; scores are O(10) so no overflow risk in fp32.
      float sc = acc2.x + acc2.y + (bb[j] - 4.0f);
      float p = __expf(sc);
      l += p;
      ax = fmaf(p * dx[j], vw4.x, ax);
      ay = fmaf(p * dy[j], vw4.y, ay);
      az = fmaf(p * dz[j], vw4.z, az);
    }
  };

  // prefetch iter 0
  float4 nb0 = *reinterpret_cast<const float4*>(biasp);
  float4 nb1 = *reinterpret_cast<const float4*>(biasp + 4);
  float4 ne0 = *reinterpret_cast<const float4*>(dpp);
  float4 ne1 = *reinterpret_cast<const float4*>(dpp + 4);
  float4 ne2 = *reinterpret_cast<const float4*>(dpp + 8);
  float4 ne3 = *reinterpret_cast<const float4*>(dpp + 12);
  float4 ne4 = *reinterpret_cast<const float4*>(dpp + 16);
  float4 ne5 = *reinterpret_cast<const float4*>(dpp + 20);

  for (int t0 = 0; t0 < S_; t0 += 8) {
    float4 b0 = nb0, b1 = nb1;
    float4 e0 = ne0, e1 = ne1, e2 = ne2, e3 = ne3, e4 = ne4, e5 = ne5;
    int tn = (t0 + 8 < S_) ? t0 + 8 : 0;  // last iter: dummy reload (cached)
    nb0 = *reinterpret_cast<const float4*>(biasp + tn);
    nb1 = *reinterpret_cast<const float4*>(biasp + tn + 4);
    const float* dpn = dpp + (size_t)tn * 3;
    ne0 = *reinterpret_cast<const float4*>(dpn);
    ne1 = *reinterpret_cast<const float4*>(dpn + 4);
    ne2 = *reinterpret_cast<const float4*>(dpn + 8);
    ne3 = *reinterpret_cast<const float4*>(dpn + 12);
    ne4 = *reinterpret_cast<const float4*>(dpn + 16);
    ne5 = *reinterpret_cast<const float4*>(dpn + 20);

    group(t0, b0, e0, e1, e2);
    group(t0 + 4, b1, e3, e4, e5);
  }

  float inv = 1.0f / l;
  float* op = out + (size_t)(b * S_ + s) * 3;
  atomicAdd(op + 0, ax * inv);
  atomicAdd(op + 1, ay * inv);
  atomicAdd(op + 2, az * inv);
}

// ---------------------------------------------------------------------------
extern "C" void kernel_launch(void* const* d_in, const int* in_sizes, int n_in,
                              void* d_out, int out_size, void* d_ws, size_t ws_size,
                              hipStream_t stream)
{
  const float* feats     = (const float*)d_in[0];
  const float* attn_bias = (const float*)d_in[1];
  const float* delta_pos = (const float*)d_in[2];
  const float* Wq        = (const float*)d_in[3];
  const float* bq        = (const float*)d_in[4];
  const float* Wk        = (const float*)d_in[5];
  const float* bk        = (const float*)d_in[6];
  const float* Wv        = (const float*)d_in[7];
  const float* bv        = (const float*)d_in[8];
  const float* Wfx       = (const float*)d_in[9];
  const float* Wfy       = (const float*)d_in[10];
  const float* Wfz       = (const float*)d_in[11];

  char* ws = (char*)d_ws;
  size_t off = 0;
  auto alloc = [&](size_t bytes) -> void* {
    void* p = ws + off;
    off = (off + bytes + 255) & ~(size_t)255;
    return p;
  };
  bf16*  ws_fb   = (bf16*) alloc((size_t)B_ * S_ * E_ * 2);        // feats bf16
  bf16*  ws_q    = (bf16*) alloc((size_t)B_ * H_ * S_ * D_ * 2);
  bf16*  ws_k    = (bf16*) alloc((size_t)B_ * H_ * S_ * D_ * 2);
  float* ws_vw   = (float*)alloc((size_t)3 * B_ * H_ * S_ * 4);
  bf16*  ws_Wt   = (bf16*) alloc((size_t)NTOT * E_ * 2);
  float* ws_bias = (float*)alloc((size_t)NTOT * 4);

  // fp32 output accumulated by attn_kernel; poisoned before timed launches
  hipMemsetAsync(d_out, 0, (size_t)B_ * S_ * 3 * 4, stream);

  int n4 = B_ * S_ * E_ / 4;
  cast_feats<<<(n4 + 255) / 256, 256, 0, stream>>>(feats, ws_fb, n4);

  int prep_n = NTOT * E_ + NTOT;
  prep_pack<<<(prep_n + 255) / 256, 256, 0, stream>>>(
      Wq, Wk, Wv, bq, bk, bv, Wfx, Wfy, Wfz, ws_Wt, ws_bias);

  gemm_qkv<<<dim3(NTOT / 128, B_ * S_ / 128), 256, 0, stream>>>(
      ws_fb, ws_Wt, ws_bias, ws_q, ws_k, ws_vw);

  attn_kernel<<<B_ * H_, 256, 0, stream>>>(ws_q, ws_k, ws_vw, attn_bias,
                                           delta_pos, (float*)d_out);
}